// Round 12
// baseline (132.071 us; speedup 1.0000x reference)
//
#include <hip/hip_runtime.h>
#include <hip/hip_bf16.h>

#define B 2048
#define NH 8
#define HD 64
#define DIM 512
#define QKVN 1536
#define OUT0_ELEMS ((size_t)B * DIM)        // 1,048,576

typedef float f32x4 __attribute__((ext_vector_type(4)));
typedef __bf16 bf16x8 __attribute__((ext_vector_type(8)));

static __device__ __forceinline__ unsigned short f2bf(float f) {
    unsigned int u = __builtin_bit_cast(unsigned int, f);
    u += 0x7fffu + ((u >> 16) & 1u);   // RNE
    return (unsigned short)(u >> 16);
}
static __device__ __forceinline__ float bfhi2f(unsigned int u) {
    return __builtin_bit_cast(float, u & 0xffff0000u);
}
static __device__ __forceinline__ float bflo2f(unsigned int u) {
    return __builtin_bit_cast(float, u << 16);
}

// ---------------------------------------------------------------------------
// K0: all input casts + accumulator zeroing in one launch.
// blocks [0,1280): x (1M) + W_proj (256K) flat cast
// blocks [1280,1472): W_qkv cast+transpose -> wT [1536][512]
// blocks [1472,1505): zero rowsum/colsum/sums/ssums
// ---------------------------------------------------------------------------
__global__ __launch_bounds__(256) void prep_cast(const float* __restrict__ x,
                                                 const float* __restrict__ wp,
                                                 const float* __restrict__ wqkv,
                                                 unsigned short* __restrict__ xbf,
                                                 unsigned short* __restrict__ wpbf,
                                                 unsigned short* __restrict__ wT,
                                                 float* __restrict__ zero_region) {
    int bx = blockIdx.x;
    int tid = threadIdx.x;
    if (bx < 1280) {
        size_t t = (size_t)bx * 256 + tid;
        const float4* src;
        ushort4* dst;
        size_t idx;
        if (t < 262144) { src = (const float4*)x; dst = (ushort4*)xbf; idx = t; }
        else            { src = (const float4*)wp; dst = (ushort4*)wpbf; idx = t - 262144; }
        float4 v = src[idx];
        ushort4 u;
        u.x = f2bf(v.x); u.y = f2bf(v.y); u.z = f2bf(v.z); u.w = f2bf(v.w);
        dst[idx] = u;
        return;
    }
    if (bx >= 1472) {
        int idx = (bx - 1472) * 256 + tid;
        if (idx < 8448)   // (2*NH*B + 2*DIM)/4 float4s
            ((float4*)zero_region)[idx] = make_float4(0.f, 0.f, 0.f, 0.f);
        return;
    }
    int b = bx - 1280;                 // 0..191
    int n0 = (b % 24) * 64;
    int k0 = (b / 24) * 64;
    __shared__ unsigned short T[64][72];   // [n][k]
#pragma unroll
    for (int it = 0; it < 4; ++it) {
        int chunk = it * 256 + tid;
        int r = chunk >> 4, c4 = (chunk & 15) * 4;
        float4 v = *(const float4*)(wqkv + (size_t)(k0 + r) * QKVN + n0 + c4);
        T[c4 + 0][r] = f2bf(v.x); T[c4 + 1][r] = f2bf(v.y);
        T[c4 + 2][r] = f2bf(v.z); T[c4 + 3][r] = f2bf(v.w);
    }
    __syncthreads();
#pragma unroll
    for (int it = 0; it < 2; ++it) {
        int chunk = it * 256 + tid;
        int r = chunk >> 3, c8 = (chunk & 7) * 8;
        ushort4 u0, u1;
        u0.x = T[r][c8 + 0]; u0.y = T[r][c8 + 1]; u0.z = T[r][c8 + 2]; u0.w = T[r][c8 + 3];
        u1.x = T[r][c8 + 4]; u1.y = T[r][c8 + 5]; u1.z = T[r][c8 + 6]; u1.w = T[r][c8 + 7];
        *(ushort4*)(wT + (size_t)(n0 + r) * 512 + k0 + c8) = u0;
        *(ushort4*)(wT + (size_t)(n0 + r) * 512 + k0 + c8 + 4) = u1;
    }
}

// ---------------------------------------------------------------------------
// K1: qkv = x @ W_qkv via bf16 MFMA. Tile 128m x 64n, 4 waves (2x2).
// q,k cols -> qkbf [B][1024]; v cols -> vT[h][d][k] (transposed) + v_f32
// ---------------------------------------------------------------------------
__global__ __launch_bounds__(256) void gemm_qkv_mfma(const unsigned short* __restrict__ xbf,
                                                     const unsigned short* __restrict__ wT,
                                                     float* __restrict__ v_f32,
                                                     unsigned short* __restrict__ qkbf,
                                                     unsigned short* __restrict__ vT) {
    int nt = blockIdx.x;   // 0..23
    int mt = blockIdx.y;   // 0..15
    __shared__ uint4 Ax[128 * 8];
    __shared__ uint4 Bw[64 * 8];
    int tid = threadIdx.x;
    int l = tid & 63, wid = tid >> 6;
    int wr = wid >> 1, wc = wid & 1;
    const uint4* x4 = (const uint4*)xbf;
    const uint4* w4 = (const uint4*)wT;
    f32x4 acc[4][2];
#pragma unroll
    for (int i = 0; i < 4; ++i)
#pragma unroll
        for (int j = 0; j < 2; ++j) acc[i][j] = (f32x4){0.f, 0.f, 0.f, 0.f};

    for (int kt = 0; kt < 8; ++kt) {
        int kg = kt * 8;
#pragma unroll
        for (int it = 0; it < 4; ++it) {
            int chunk = it * 256 + tid;
            int row = chunk >> 3, slot = chunk & 7;
            Ax[row * 8 + (slot ^ (row & 7))] = x4[(size_t)(mt * 128 + row) * 64 + kg + slot];
        }
#pragma unroll
        for (int it = 0; it < 2; ++it) {
            int chunk = it * 256 + tid;
            int row = chunk >> 3, slot = chunk & 7;
            Bw[row * 8 + (slot ^ (row & 7))] = w4[(size_t)(nt * 64 + row) * 64 + kg + slot];
        }
        __syncthreads();
#pragma unroll
        for (int km = 0; km < 2; ++km) {
            int gsel = km * 4 + (l >> 4);
            bf16x8 a[4], b[2];
#pragma unroll
            for (int i = 0; i < 4; ++i) {
                int row = wr * 64 + i * 16 + (l & 15);
                a[i] = __builtin_bit_cast(bf16x8, Ax[row * 8 + (gsel ^ (row & 7))]);
            }
#pragma unroll
            for (int j = 0; j < 2; ++j) {
                int row = wc * 32 + j * 16 + (l & 15);
                b[j] = __builtin_bit_cast(bf16x8, Bw[row * 8 + (gsel ^ (row & 7))]);
            }
#pragma unroll
            for (int i = 0; i < 4; ++i)
#pragma unroll
                for (int j = 0; j < 2; ++j)
                    acc[i][j] = __builtin_amdgcn_mfma_f32_16x16x32_bf16(a[i], b[j], acc[i][j], 0, 0, 0);
        }
        __syncthreads();
    }
    if (nt < 16) {
#pragma unroll
        for (int i = 0; i < 4; ++i)
#pragma unroll
            for (int j = 0; j < 2; ++j)
#pragma unroll
                for (int reg = 0; reg < 4; ++reg) {
                    int row = mt * 128 + wr * 64 + i * 16 + (l >> 4) * 4 + reg;
                    int col = nt * 64 + wc * 32 + j * 16 + (l & 15);
                    qkbf[(size_t)row * 1024 + col] = f2bf(acc[i][j][reg]);
                }
    } else {
        int h = nt - 16;   // head
#pragma unroll
        for (int i = 0; i < 4; ++i)
#pragma unroll
            for (int j = 0; j < 2; ++j) {
                int k0r = mt * 128 + wr * 64 + i * 16 + (l >> 4) * 4;
                int d = wc * 32 + j * 16 + (l & 15);
                uint2 pk;
                pk.x = (unsigned)f2bf(acc[i][j][0]) | ((unsigned)f2bf(acc[i][j][1]) << 16);
                pk.y = (unsigned)f2bf(acc[i][j][2]) | ((unsigned)f2bf(acc[i][j][3]) << 16);
                *(uint2*)(vT + ((size_t)(h * 64 + d) * 2048 + k0r)) = pk;
#pragma unroll
                for (int reg = 0; reg < 4; ++reg)
                    v_f32[(size_t)(k0r + reg) * DIM + h * 64 + d] = acc[i][j][reg];
            }
    }
}

// ---------------------------------------------------------------------------
// K3: attention pass (R9 measured-best shapes). PHASE 1: rowsums only.
// PHASE 2: recompute QK^T, normalize, nt-vector-write P, colsum, PV via MFMA.
// grid (4 ct, 16 qt of 128q, 8 h) = 512 blocks, 4 waves 2x2.
// ---------------------------------------------------------------------------
template<int PHASE>
__global__ __launch_bounds__(256) void attn_pass(const unsigned short* __restrict__ qkbf,
                                                 const unsigned short* __restrict__ vT,
                                                 const float* __restrict__ rowsum_in,
                                                 float* __restrict__ rowsum_out,
                                                 float* __restrict__ attn,
                                                 float* __restrict__ colsum,
                                                 float* __restrict__ ovp) {
    int ct = blockIdx.x, qt = blockIdx.y, h = blockIdx.z;
    int tid = threadIdx.x;
    int l = tid & 63;
    int wid = tid >> 6;
    int wr = wid >> 1;
    int wc = wid & 1;

    __shared__ uint4 Qs[128 * 8];
    __shared__ uint4 Ks[64 * 8];
    __shared__ uint4 Vt[64 * 8];
    __shared__ uint4 Pl4[128 * 8];
    __shared__ float cs[512];
    __shared__ float rinv[128];
    unsigned short* Pl = (unsigned short*)Pl4;

    const uint4* src = (const uint4*)qkbf;   // row = 128 uint4
#pragma unroll
    for (int it = 0; it < 4; ++it) {
        int chunk = it * 256 + tid;
        int row = chunk >> 3, slot = chunk & 7;
        Qs[row * 8 + (slot ^ (row & 7))] = src[(size_t)(qt * 128 + row) * 128 + h * 8 + slot];
    }
    if constexpr (PHASE == 2) {
        if (tid < 128) rinv[tid] = 1.0f / rowsum_in[h * B + qt * 128 + tid];
        if (tid < 256) { cs[tid] = 0.f; cs[tid + 256] = 0.f; }
    }

    float rsum[4][4];
    f32x4 O[4][2];
    if constexpr (PHASE == 1) {
#pragma unroll
        for (int i = 0; i < 4; ++i)
#pragma unroll
            for (int r = 0; r < 4; ++r) rsum[i][r] = 0.f;
    } else {
#pragma unroll
        for (int i = 0; i < 4; ++i)
#pragma unroll
            for (int j = 0; j < 2; ++j) O[i][j] = (f32x4){0.f, 0.f, 0.f, 0.f};
    }

    size_t hbb = (size_t)h * B * B;
    for (int sub = 0; sub < 8; ++sub) {
        int kbase = ct * 512 + sub * 64;
#pragma unroll
        for (int it = 0; it < 2; ++it) {
            int chunk = it * 256 + tid;
            int row = chunk >> 3, slot = chunk & 7;
            Ks[row * 8 + (slot ^ (row & 7))] = src[(size_t)(kbase + row) * 128 + 64 + h * 8 + slot];
        }
        if constexpr (PHASE == 2) {
#pragma unroll
            for (int it = 0; it < 2; ++it) {
                int chunk = it * 256 + tid;
                int d = chunk >> 3, g = chunk & 7;
                Vt[d * 8 + (g ^ (d & 7))] =
                    *(const uint4*)(vT + ((size_t)(h * 64 + d) * 2048 + kbase + g * 8));
            }
        }
        __syncthreads();

        // ---- QK^T ----
        f32x4 S[4][2];
#pragma unroll
        for (int i = 0; i < 4; ++i)
#pragma unroll
            for (int j = 0; j < 2; ++j) S[i][j] = (f32x4){0.f, 0.f, 0.f, 0.f};
#pragma unroll
        for (int km = 0; km < 2; ++km) {
            int gsel = km * 4 + (l >> 4);
            bf16x8 aq[4], bk[2];
#pragma unroll
            for (int i = 0; i < 4; ++i) {
                int row = wr * 64 + i * 16 + (l & 15);
                aq[i] = __builtin_bit_cast(bf16x8, Qs[row * 8 + (gsel ^ (row & 7))]);
            }
#pragma unroll
            for (int j = 0; j < 2; ++j) {
                int row = wc * 32 + j * 16 + (l & 15);
                bk[j] = __builtin_bit_cast(bf16x8, Ks[row * 8 + (gsel ^ (row & 7))]);
            }
#pragma unroll
            for (int i = 0; i < 4; ++i)
#pragma unroll
                for (int j = 0; j < 2; ++j)
                    S[i][j] = __builtin_amdgcn_mfma_f32_16x16x32_bf16(aq[i], bk[j], S[i][j], 0, 0, 0);
        }

        if constexpr (PHASE == 1) {
#pragma unroll
            for (int i = 0; i < 4; ++i)
#pragma unroll
                for (int j = 0; j < 2; ++j)
#pragma unroll
                    for (int reg = 0; reg < 4; ++reg)
                        rsum[i][reg] += __expf(S[i][j][reg] * 0.125f);
            __syncthreads();
        } else {
            float csacc[2] = {0.f, 0.f};
#pragma unroll
            for (int i = 0; i < 4; ++i) {
#pragma unroll
                for (int j = 0; j < 2; ++j) {
                    int kcol = wc * 32 + j * 16 + (l & 15);
#pragma unroll
                    for (int reg = 0; reg < 4; ++reg) {
                        int qrow = wr * 64 + i * 16 + (l >> 4) * 4 + reg;
                        float p = __expf(S[i][j][reg] * 0.125f) * rinv[qrow];
                        csacc[j] += p;
                        Pl[qrow * 64 + ((kcol & 7) | ((((kcol >> 3) ^ (qrow & 7))) << 3))] = f2bf(p);
                    }
                }
            }
#pragma unroll
            for (int j = 0; j < 2; ++j) {
                float v = csacc[j];
                v += __shfl_xor(v, 16);
                v += __shfl_xor(v, 32);
                if (l < 16) atomicAdd(&cs[sub * 64 + wc * 32 + j * 16 + l], v);
            }
            __syncthreads();
            // ---- nt vector store of attn from Pl stash (bf16-rounded) ----
#pragma unroll
            for (int it2 = 0; it2 < 4; ++it2) {
                int chunk = it2 * 256 + tid;
                int row = chunk >> 3, g = chunk & 7;
                uint4 pv = Pl4[row * 8 + (g ^ (row & 7))];
                f32x4 lo, hi;
                lo.x = bflo2f(pv.x); lo.y = bfhi2f(pv.x);
                lo.z = bflo2f(pv.y); lo.w = bfhi2f(pv.y);
                hi.x = bflo2f(pv.z); hi.y = bfhi2f(pv.z);
                hi.z = bflo2f(pv.w); hi.w = bfhi2f(pv.w);
                float* dst = attn + hbb + (size_t)(qt * 128 + row) * B + kbase + g * 8;
                __builtin_nontemporal_store(lo, (f32x4*)dst);
                __builtin_nontemporal_store(hi, (f32x4*)(dst + 4));
            }
#pragma unroll
            for (int km = 0; km < 2; ++km) {
                int gsel = km * 4 + (l >> 4);
                bf16x8 pa[4], vb[2];
#pragma unroll
                for (int i = 0; i < 4; ++i) {
                    int q = wr * 64 + i * 16 + (l & 15);
                    pa[i] = __builtin_bit_cast(bf16x8, Pl4[q * 8 + (gsel ^ (q & 7))]);
                }
#pragma unroll
                for (int j = 0; j < 2; ++j) {
                    int d = wc * 32 + j * 16 + (l & 15);
                    vb[j] = __builtin_bit_cast(bf16x8, Vt[d * 8 + (gsel ^ (d & 7))]);
                }
#pragma unroll
                for (int i = 0; i < 4; ++i)
#pragma unroll
                    for (int j = 0; j < 2; ++j)
                        O[i][j] = __builtin_amdgcn_mfma_f32_16x16x32_bf16(pa[i], vb[j], O[i][j], 0, 0, 0);
            }
            __syncthreads();
        }
    }

    if constexpr (PHASE == 1) {
#pragma unroll
        for (int i = 0; i < 4; ++i)
#pragma unroll
            for (int reg = 0; reg < 4; ++reg) {
                float v = rsum[i][reg];
                v += __shfl_xor(v, 1); v += __shfl_xor(v, 2);
                v += __shfl_xor(v, 4); v += __shfl_xor(v, 8);
                if ((l & 15) == 0)
                    atomicAdd(&rowsum_out[h * B + qt * 128 + wr * 64 + i * 16 + (l >> 4) * 4 + reg], v);
            }
    } else {
        for (int i = tid; i < 512; i += 256)
            atomicAdd(&colsum[h * B + ct * 512 + i], cs[i]);
#pragma unroll
        for (int i = 0; i < 4; ++i)
#pragma unroll
            for (int j = 0; j < 2; ++j)
#pragma unroll
                for (int reg = 0; reg < 4; ++reg) {
                    int qrow = wr * 64 + i * 16 + (l >> 4) * 4 + reg;
                    ovp[((size_t)ct * B + qt * 128 + qrow) * DIM + h * 64 + wc * 32 + j * 16 + (l & 15)] =
                        O[i][j][reg];
                }
    }
}

// ---------------------------------------------------------------------------
// K5: maskfix with fused per-block top-5 (deterministic redundant scan).
// grid (32 rt, 8 h).
// ---------------------------------------------------------------------------
__global__ __launch_bounds__(256) void maskfix_topk(float* __restrict__ attn,
                                                    const float* __restrict__ v_f32,
                                                    const float* __restrict__ colsum,
                                                    const float* __restrict__ ovp,
                                                    unsigned short* __restrict__ ovbf) {
    int rt = blockIdx.x;
    int h = blockIdx.y;
    int tid = threadIdx.x;
    __shared__ float v[B];
    __shared__ float bv[256];
    __shared__ int bi[256];
    __shared__ float Pl[5][64];
    __shared__ float Vl[5][64];
    __shared__ int tix[5];
    for (int i = tid; i < B; i += 256) v[i] = colsum[h * B + i];
    __syncthreads();
    for (int it = 0; it < 5; ++it) {
        float best = -1e30f;
        int bidx = 0;
        for (int i = tid; i < B; i += 256) {
            float x = v[i];
            if (x > best || (x == best && i < bidx)) { best = x; bidx = i; }
        }
        bv[tid] = best; bi[tid] = bidx;
        __syncthreads();
        for (int s = 128; s > 0; s >>= 1) {
            if (tid < s) {
                if (bv[tid + s] > bv[tid] ||
                    (bv[tid + s] == bv[tid] && bi[tid + s] < bi[tid])) {
                    bv[tid] = bv[tid + s]; bi[tid] = bi[tid + s];
                }
            }
            __syncthreads();
        }
        if (tid == 0) { tix[it] = bi[0]; v[bi[0]] = -1e30f; }
        __syncthreads();
    }
    size_t abase = (size_t)h * B * B + (size_t)(rt * 64) * B;
    for (int t = tid; t < 320; t += 256) {
        int i = t / 64, q = t % 64;
        Pl[i][q] = attn[abase + (size_t)q * B + tix[i]];
        Vl[i][q] = v_f32[(size_t)tix[i] * DIM + h * 64 + q];
    }
    __syncthreads();
    for (int t = tid; t < 320; t += 256) {
        int i = t / 64, q = t % 64;
        attn[abase + (size_t)q * B + tix[i]] = 0.f;
    }
    int tx = tid % 16, ty = tid / 16;
    float corr[4][4] = {};
#pragma unroll
    for (int i = 0; i < 5; ++i)
#pragma unroll
        for (int a = 0; a < 4; ++a)
#pragma unroll
            for (int b2 = 0; b2 < 4; ++b2)
                corr[a][b2] += Pl[i][ty * 4 + a] * Vl[i][tx * 4 + b2];
#pragma unroll
    for (int a = 0; a < 4; ++a) {
        size_t row = (size_t)(rt * 64 + ty * 4 + a);
        size_t col = h * 64 + tx * 4;
        float4 s0 = *(const float4*)(ovp + ((size_t)0 * B + row) * DIM + col);
        float4 s1 = *(const float4*)(ovp + ((size_t)1 * B + row) * DIM + col);
        float4 s2 = *(const float4*)(ovp + ((size_t)2 * B + row) * DIM + col);
        float4 s3 = *(const float4*)(ovp + ((size_t)3 * B + row) * DIM + col);
        ushort4 u;
        u.x = f2bf(s0.x + s1.x + s2.x + s3.x - corr[a][0]);
        u.y = f2bf(s0.y + s1.y + s2.y + s3.y - corr[a][1]);
        u.z = f2bf(s0.z + s1.z + s2.z + s3.z - corr[a][2]);
        u.w = f2bf(s0.w + s1.w + s2.w + s3.w - corr[a][3]);
        *(ushort4*)(ovbf + row * DIM + col) = u;
    }
}

// ---------------------------------------------------------------------------
// K7: y = ov @ W_proj^T + b_proj via bf16 MFMA; fused BN partial sums.
// ---------------------------------------------------------------------------
__global__ __launch_bounds__(256) void proj_gemm_mfma(const unsigned short* __restrict__ ovbf,
                                                      const unsigned short* __restrict__ wpbf,
                                                      const float* __restrict__ bproj,
                                                      float* __restrict__ y,
                                                      float* __restrict__ sums,
                                                      float* __restrict__ ssums) {
    int nt = blockIdx.x;   // 0..7
    int mt = blockIdx.y;   // 0..15
    __shared__ uint4 Ax[128 * 8];
    __shared__ uint4 Bw[64 * 8];
    __shared__ float sb[64];
    __shared__ float qb[64];
    int tid = threadIdx.x;
    int l = tid & 63, wid = tid >> 6;
    int wr = wid >> 1, wc = wid & 1;
    if (tid < 64) { sb[tid] = 0.f; qb[tid] = 0.f; }
    const uint4* a4 = (const uint4*)ovbf;
    const uint4* b4 = (const uint4*)wpbf;
    f32x4 acc[4][2];
#pragma unroll
    for (int i = 0; i < 4; ++i)
#pragma unroll
        for (int j = 0; j < 2; ++j) acc[i][j] = (f32x4){0.f, 0.f, 0.f, 0.f};

    for (int kt = 0; kt < 8; ++kt) {
        int kg = kt * 8;
#pragma unroll
        for (int it = 0; it < 4; ++it) {
            int chunk = it * 256 + tid;
            int row = chunk >> 3, slot = chunk & 7;
            Ax[row * 8 + (slot ^ (row & 7))] = a4[(size_t)(mt * 128 + row) * 64 + kg + slot];
        }
#pragma unroll
        for (int it = 0; it < 2; ++it) {
            int chunk = it * 256 + tid;
            int row = chunk >> 3, slot = chunk & 7;
            Bw[row * 8 + (slot ^ (row & 7))] = b4[(size_t)(nt * 64 + row) * 64 + kg + slot];
        }
        __syncthreads();
#pragma unroll
        for (int km = 0; km < 2; ++km) {
            int gsel = km * 4 + (l >> 4);
            bf16x8 a[4], b[2];
#pragma unroll
            for (int i = 0; i < 4; ++i) {
                int row = wr * 64 + i * 16 + (l & 15);
                a[i] = __builtin_bit_cast(bf16x8, Ax[row * 8 + (gsel ^ (row & 7))]);
            }
#pragma unroll
            for (int j = 0; j < 2; ++j) {
                int row = wc * 32 + j * 16 + (l & 15);
                b[j] = __builtin_bit_cast(bf16x8, Bw[row * 8 + (gsel ^ (row & 7))]);
            }
#pragma unroll
            for (int i = 0; i < 4; ++i)
#pragma unroll
                for (int j = 0; j < 2; ++j)
                    acc[i][j] = __builtin_amdgcn_mfma_f32_16x16x32_bf16(a[i], b[j], acc[i][j], 0, 0, 0);
        }
        __syncthreads();
    }
    float ls[2] = {0.f, 0.f};
    float lq[2] = {0.f, 0.f};
#pragma unroll
    for (int i = 0; i < 4; ++i)
#pragma unroll
        for (int j = 0; j < 2; ++j) {
            int col = nt * 64 + wc * 32 + j * 16 + (l & 15);
            float bp = bproj[col];
#pragma unroll
            for (int reg = 0; reg < 4; ++reg) {
                int row = mt * 128 + wr * 64 + i * 16 + (l >> 4) * 4 + reg;
                float c = acc[i][j][reg] + bp;
                y[(size_t)row * DIM + col] = c;
                ls[j] += c; lq[j] += c * c;
            }
        }
#pragma unroll
    for (int j = 0; j < 2; ++j) {
        atomicAdd(&sb[wc * 32 + j * 16 + (l & 15)], ls[j]);
        atomicAdd(&qb[wc * 32 + j * 16 + (l & 15)], lq[j]);
    }
    __syncthreads();
    if (tid < 64) {
        atomicAdd(&sums[nt * 64 + tid], sb[tid]);
        atomicAdd(&ssums[nt * 64 + tid], qb[tid]);
    }
}

// ---------------------------------------------------------------------------
// K9: out = relu(gamma*(y-mean)*rstd + beta); mean/rstd from sums inline
// ---------------------------------------------------------------------------
__global__ __launch_bounds__(256) void bn_apply(const float* __restrict__ y,
                                                const float* __restrict__ sums,
                                                const float* __restrict__ ssums,
                                                const float* __restrict__ gamma,
                                                const float* __restrict__ beta,
                                                float* __restrict__ out) {
    int t = blockIdx.x * 256 + threadIdx.x;
    int c4 = (t % 128) * 4;
    size_t r = t / 128;
    if (r >= B) return;
    float4 s = *(const float4*)(sums + c4);
    float4 q = *(const float4*)(ssums + c4);
    float4 m, rs;
    m.x = s.x * (1.0f / B); m.y = s.y * (1.0f / B);
    m.z = s.z * (1.0f / B); m.w = s.w * (1.0f / B);
    rs.x = rsqrtf(q.x * (1.0f / B) - m.x * m.x + 1e-5f);
    rs.y = rsqrtf(q.y * (1.0f / B) - m.y * m.y + 1e-5f);
    rs.z = rsqrtf(q.z * (1.0f / B) - m.z * m.z + 1e-5f);
    rs.w = rsqrtf(q.w * (1.0f / B) - m.w * m.w + 1e-5f);
    float4 v = *(const float4*)(y + r * DIM + c4);
    float4 g = *(const float4*)(gamma + c4);
    float4 bt = *(const float4*)(beta + c4);
    f32x4 o;
    o.x = fmaxf(0.f, g.x * (v.x - m.x) * rs.x + bt.x);
    o.y = fmaxf(0.f, g.y * (v.y - m.y) * rs.y + bt.y);
    o.z = fmaxf(0.f, g.z * (v.z - m.z) * rs.z + bt.z);
    o.w = fmaxf(0.f, g.w * (v.w - m.w) * rs.w + bt.w);
    __builtin_nontemporal_store(o, (f32x4*)(out + r * DIM + c4));
}

// ---------------------------------------------------------------------------
extern "C" void kernel_launch(void* const* d_in, const int* in_sizes, int n_in,
                              void* d_out, int out_size, void* d_ws, size_t ws_size,
                              hipStream_t stream) {
    const float* x = (const float*)d_in[0];
    const float* W_qkv = (const float*)d_in[1];
    const float* W_proj = (const float*)d_in[2];
    const float* b_proj = (const float*)d_in[3];
    const float* bn_gamma = (const float*)d_in[4];
    const float* bn_beta = (const float*)d_in[5];

    float* out0 = (float*)d_out;                         // [2048,512]
    float* attn = (float*)d_out + OUT0_ELEMS;            // [8,2048,2048]

    float* ws = (float*)d_ws;
    float* v_f32 = ws;                                   // 1,048,576 f
    float* ovp = v_f32 + OUT0_ELEMS;                     // 4,194,304 f
    float* y = ovp + 4 * OUT0_ELEMS;                     // 1,048,576 f
    // zero region (contiguous, zeroed by prep_cast): rowsum, colsum, sums, ssums
    float* rowsum = y + OUT0_ELEMS;                      // 16,384 f
    float* colsum = rowsum + NH * B;                     // 16,384 f
    float* sums = colsum + NH * B;                       // 512 f
    float* ssums = sums + DIM;                           // 512 f
    unsigned short* qkbf = (unsigned short*)(ssums + DIM);       // B*1024 us
    unsigned short* vT = qkbf + (size_t)B * 1024;                // NH*HD*B us
    unsigned short* wpbf = vT + (size_t)NH * HD * B;             // 512*512 us
    unsigned short* ovbf = wpbf + (size_t)DIM * DIM;             // B*DIM us
    // xbf (2 MB) + wT (1.5 MB) alias ovp: consumed by gemm_qkv_mfma, which
    // completes before attn_pass<2> writes ovp.
    unsigned short* xbf = (unsigned short*)ovp;
    unsigned short* wT = xbf + (size_t)B * 512;

    prep_cast<<<1280 + 192 + 33, 256, 0, stream>>>(x, W_proj, W_qkv, xbf, wpbf, wT, rowsum);
    gemm_qkv_mfma<<<dim3(QKVN / 64, B / 128), 256, 0, stream>>>(xbf, wT, v_f32, qkbf, vT);
    attn_pass<1><<<dim3(4, 16, NH), 256, 0, stream>>>(qkbf, vT, nullptr, rowsum,
                                                      attn, colsum, ovp);
    attn_pass<2><<<dim3(4, 16, NH), 256, 0, stream>>>(qkbf, vT, rowsum, nullptr,
                                                      attn, colsum, ovp);
    maskfix_topk<<<dim3(B / 64, NH), 256, 0, stream>>>(attn, v_f32, colsum, ovp, ovbf);
    proj_gemm_mfma<<<dim3(DIM / 64, B / 128), 256, 0, stream>>>(ovbf, wpbf, b_proj,
                                                                y, sums, ssums);
    bn_apply<<<(B * DIM / 4 + 255) / 256, 256, 0, stream>>>(y, sums, ssums,
                                                            bn_gamma, bn_beta, out0);
}

// Round 13
// 104.533 us; speedup vs baseline: 1.2634x; 1.2634x over previous
//
#include <hip/hip_runtime.h>
#include <hip/hip_bf16.h>

#define B 2048
#define NH 8
#define HD 64
#define DIM 512
#define QKVN 1536
#define OUT0_ELEMS ((size_t)B * DIM)        // 1,048,576

typedef float f32x4 __attribute__((ext_vector_type(4)));
typedef __bf16 bf16x8 __attribute__((ext_vector_type(8)));

static __device__ __forceinline__ unsigned short f2bf(float f) {
    unsigned int u = __builtin_bit_cast(unsigned int, f);
    u += 0x7fffu + ((u >> 16) & 1u);   // RNE
    return (unsigned short)(u >> 16);
}
static __device__ __forceinline__ float bfhi2f(unsigned int u) {
    return __builtin_bit_cast(float, u & 0xffff0000u);
}
static __device__ __forceinline__ float bflo2f(unsigned int u) {
    return __builtin_bit_cast(float, u << 16);
}

// ---------------------------------------------------------------------------
// K0: all input casts in one launch.
// blocks [0,1280): x (1M) + W_proj (256K) flat cast
// blocks [1280,1472): W_qkv cast+transpose -> wT [1536][512]
// ---------------------------------------------------------------------------
__global__ __launch_bounds__(256) void prep_cast(const float* __restrict__ x,
                                                 const float* __restrict__ wp,
                                                 const float* __restrict__ wqkv,
                                                 unsigned short* __restrict__ xbf,
                                                 unsigned short* __restrict__ wpbf,
                                                 unsigned short* __restrict__ wT) {
    int bx = blockIdx.x;
    int tid = threadIdx.x;
    if (bx < 1280) {
        size_t t = (size_t)bx * 256 + tid;
        const float4* src;
        ushort4* dst;
        size_t idx;
        if (t < 262144) { src = (const float4*)x; dst = (ushort4*)xbf; idx = t; }
        else            { src = (const float4*)wp; dst = (ushort4*)wpbf; idx = t - 262144; }
        float4 v = src[idx];
        ushort4 u;
        u.x = f2bf(v.x); u.y = f2bf(v.y); u.z = f2bf(v.z); u.w = f2bf(v.w);
        dst[idx] = u;
        return;
    }
    int b = bx - 1280;                 // 0..191
    int n0 = (b % 24) * 64;
    int k0 = (b / 24) * 64;
    __shared__ unsigned short T[64][72];   // [n][k]
#pragma unroll
    for (int it = 0; it < 4; ++it) {
        int chunk = it * 256 + tid;
        int r = chunk >> 4, c4 = (chunk & 15) * 4;
        float4 v = *(const float4*)(wqkv + (size_t)(k0 + r) * QKVN + n0 + c4);
        T[c4 + 0][r] = f2bf(v.x); T[c4 + 1][r] = f2bf(v.y);
        T[c4 + 2][r] = f2bf(v.z); T[c4 + 3][r] = f2bf(v.w);
    }
    __syncthreads();
#pragma unroll
    for (int it = 0; it < 2; ++it) {
        int chunk = it * 256 + tid;
        int r = chunk >> 3, c8 = (chunk & 7) * 8;
        ushort4 u0, u1;
        u0.x = T[r][c8 + 0]; u0.y = T[r][c8 + 1]; u0.z = T[r][c8 + 2]; u0.w = T[r][c8 + 3];
        u1.x = T[r][c8 + 4]; u1.y = T[r][c8 + 5]; u1.z = T[r][c8 + 6]; u1.w = T[r][c8 + 7];
        *(ushort4*)(wT + (size_t)(n0 + r) * 512 + k0 + c8) = u0;
        *(ushort4*)(wT + (size_t)(n0 + r) * 512 + k0 + c8 + 4) = u1;
    }
}

// ---------------------------------------------------------------------------
// K1: qkv = x @ W_qkv via bf16 MFMA. Tile 128m x 64n, 4 waves (2x2).
// q,k cols -> qkbf [B][1024]; v cols -> vT[h][d][k] (transposed) + v_f32
// ---------------------------------------------------------------------------
__global__ __launch_bounds__(256) void gemm_qkv_mfma(const unsigned short* __restrict__ xbf,
                                                     const unsigned short* __restrict__ wT,
                                                     float* __restrict__ v_f32,
                                                     unsigned short* __restrict__ qkbf,
                                                     unsigned short* __restrict__ vT) {
    int nt = blockIdx.x;   // 0..23
    int mt = blockIdx.y;   // 0..15
    __shared__ uint4 Ax[128 * 8];
    __shared__ uint4 Bw[64 * 8];
    int tid = threadIdx.x;
    int l = tid & 63, wid = tid >> 6;
    int wr = wid >> 1, wc = wid & 1;
    const uint4* x4 = (const uint4*)xbf;
    const uint4* w4 = (const uint4*)wT;
    f32x4 acc[4][2];
#pragma unroll
    for (int i = 0; i < 4; ++i)
#pragma unroll
        for (int j = 0; j < 2; ++j) acc[i][j] = (f32x4){0.f, 0.f, 0.f, 0.f};

    for (int kt = 0; kt < 8; ++kt) {
        int kg = kt * 8;
#pragma unroll
        for (int it = 0; it < 4; ++it) {
            int chunk = it * 256 + tid;
            int row = chunk >> 3, slot = chunk & 7;
            Ax[row * 8 + (slot ^ (row & 7))] = x4[(size_t)(mt * 128 + row) * 64 + kg + slot];
        }
#pragma unroll
        for (int it = 0; it < 2; ++it) {
            int chunk = it * 256 + tid;
            int row = chunk >> 3, slot = chunk & 7;
            Bw[row * 8 + (slot ^ (row & 7))] = w4[(size_t)(nt * 64 + row) * 64 + kg + slot];
        }
        __syncthreads();
#pragma unroll
        for (int km = 0; km < 2; ++km) {
            int gsel = km * 4 + (l >> 4);
            bf16x8 a[4], b[2];
#pragma unroll
            for (int i = 0; i < 4; ++i) {
                int row = wr * 64 + i * 16 + (l & 15);
                a[i] = __builtin_bit_cast(bf16x8, Ax[row * 8 + (gsel ^ (row & 7))]);
            }
#pragma unroll
            for (int j = 0; j < 2; ++j) {
                int row = wc * 32 + j * 16 + (l & 15);
                b[j] = __builtin_bit_cast(bf16x8, Bw[row * 8 + (gsel ^ (row & 7))]);
            }
#pragma unroll
            for (int i = 0; i < 4; ++i)
#pragma unroll
                for (int j = 0; j < 2; ++j)
                    acc[i][j] = __builtin_amdgcn_mfma_f32_16x16x32_bf16(a[i], b[j], acc[i][j], 0, 0, 0);
        }
        __syncthreads();
    }
    if (nt < 16) {
#pragma unroll
        for (int i = 0; i < 4; ++i)
#pragma unroll
            for (int j = 0; j < 2; ++j)
#pragma unroll
                for (int reg = 0; reg < 4; ++reg) {
                    int row = mt * 128 + wr * 64 + i * 16 + (l >> 4) * 4 + reg;
                    int col = nt * 64 + wc * 32 + j * 16 + (l & 15);
                    qkbf[(size_t)row * 1024 + col] = f2bf(acc[i][j][reg]);
                }
    } else {
        int h = nt - 16;   // head
#pragma unroll
        for (int i = 0; i < 4; ++i)
#pragma unroll
            for (int j = 0; j < 2; ++j) {
                int k0r = mt * 128 + wr * 64 + i * 16 + (l >> 4) * 4;
                int d = wc * 32 + j * 16 + (l & 15);
                uint2 pk;
                pk.x = (unsigned)f2bf(acc[i][j][0]) | ((unsigned)f2bf(acc[i][j][1]) << 16);
                pk.y = (unsigned)f2bf(acc[i][j][2]) | ((unsigned)f2bf(acc[i][j][3]) << 16);
                *(uint2*)(vT + ((size_t)(h * 64 + d) * 2048 + k0r)) = pk;
#pragma unroll
                for (int reg = 0; reg < 4; ++reg)
                    v_f32[(size_t)(k0r + reg) * DIM + h * 64 + d] = acc[i][j][reg];
            }
    }
}

// ---------------------------------------------------------------------------
// K3: attention pass. PHASE 1: rowsums only. PHASE 2: recompute QK^T,
//     normalize, vector-write P (from bf16 LDS stash), colsum, PV via MFMA.
// grid (4 ct, 16 qt of 128q, 8 h) = 512 blocks, 4 waves 2x2.
// ---------------------------------------------------------------------------
template<int PHASE>
__global__ __launch_bounds__(256) void attn_pass(const unsigned short* __restrict__ qkbf,
                                                 const unsigned short* __restrict__ vT,
                                                 const float* __restrict__ rowsum_in,
                                                 float* __restrict__ rowsum_out,
                                                 float* __restrict__ attn,
                                                 float* __restrict__ colsum,
                                                 float* __restrict__ ovp) {
    int ct = blockIdx.x, qt = blockIdx.y, h = blockIdx.z;
    int tid = threadIdx.x;
    int l = tid & 63;
    int wid = tid >> 6;
    int wr = wid >> 1;
    int wc = wid & 1;

    __shared__ uint4 Qs[128 * 8];
    __shared__ uint4 Ks[64 * 8];
    __shared__ uint4 Vt[64 * 8];
    __shared__ uint4 Pl4[128 * 8];
    __shared__ float cs[512];
    __shared__ float rinv[128];
    unsigned short* Pl = (unsigned short*)Pl4;

    const uint4* src = (const uint4*)qkbf;   // row = 128 uint4
#pragma unroll
    for (int it = 0; it < 4; ++it) {
        int chunk = it * 256 + tid;
        int row = chunk >> 3, slot = chunk & 7;
        Qs[row * 8 + (slot ^ (row & 7))] = src[(size_t)(qt * 128 + row) * 128 + h * 8 + slot];
    }
    if constexpr (PHASE == 2) {
        if (tid < 128) rinv[tid] = 1.0f / rowsum_in[h * B + qt * 128 + tid];
        if (tid < 256) { cs[tid] = 0.f; cs[tid + 256] = 0.f; }
    }

    float rsum[4][4];
    f32x4 O[4][2];
    if constexpr (PHASE == 1) {
#pragma unroll
        for (int i = 0; i < 4; ++i)
#pragma unroll
            for (int r = 0; r < 4; ++r) rsum[i][r] = 0.f;
    } else {
#pragma unroll
        for (int i = 0; i < 4; ++i)
#pragma unroll
            for (int j = 0; j < 2; ++j) O[i][j] = (f32x4){0.f, 0.f, 0.f, 0.f};
    }

    size_t hbb = (size_t)h * B * B;
    for (int sub = 0; sub < 8; ++sub) {
        int kbase = ct * 512 + sub * 64;
#pragma unroll
        for (int it = 0; it < 2; ++it) {
            int chunk = it * 256 + tid;
            int row = chunk >> 3, slot = chunk & 7;
            Ks[row * 8 + (slot ^ (row & 7))] = src[(size_t)(kbase + row) * 128 + 64 + h * 8 + slot];
        }
        if constexpr (PHASE == 2) {
#pragma unroll
            for (int it = 0; it < 2; ++it) {
                int chunk = it * 256 + tid;
                int d = chunk >> 3, g = chunk & 7;
                Vt[d * 8 + (g ^ (d & 7))] =
                    *(const uint4*)(vT + ((size_t)(h * 64 + d) * 2048 + kbase + g * 8));
            }
        }
        __syncthreads();

        // ---- QK^T ----
        f32x4 S[4][2];
#pragma unroll
        for (int i = 0; i < 4; ++i)
#pragma unroll
            for (int j = 0; j < 2; ++j) S[i][j] = (f32x4){0.f, 0.f, 0.f, 0.f};
#pragma unroll
        for (int km = 0; km < 2; ++km) {
            int gsel = km * 4 + (l >> 4);
            bf16x8 aq[4], bk[2];
#pragma unroll
            for (int i = 0; i < 4; ++i) {
                int row = wr * 64 + i * 16 + (l & 15);
                aq[i] = __builtin_bit_cast(bf16x8, Qs[row * 8 + (gsel ^ (row & 7))]);
            }
#pragma unroll
            for (int j = 0; j < 2; ++j) {
                int row = wc * 32 + j * 16 + (l & 15);
                bk[j] = __builtin_bit_cast(bf16x8, Ks[row * 8 + (gsel ^ (row & 7))]);
            }
#pragma unroll
            for (int i = 0; i < 4; ++i)
#pragma unroll
                for (int j = 0; j < 2; ++j)
                    S[i][j] = __builtin_amdgcn_mfma_f32_16x16x32_bf16(aq[i], bk[j], S[i][j], 0, 0, 0);
        }

        if constexpr (PHASE == 1) {
#pragma unroll
            for (int i = 0; i < 4; ++i)
#pragma unroll
                for (int j = 0; j < 2; ++j)
#pragma unroll
                    for (int reg = 0; reg < 4; ++reg)
                        rsum[i][reg] += __expf(S[i][j][reg] * 0.125f);
            __syncthreads();
        } else {
            float csacc[2] = {0.f, 0.f};
#pragma unroll
            for (int i = 0; i < 4; ++i) {
#pragma unroll
                for (int j = 0; j < 2; ++j) {
                    int kcol = wc * 32 + j * 16 + (l & 15);
#pragma unroll
                    for (int reg = 0; reg < 4; ++reg) {
                        int qrow = wr * 64 + i * 16 + (l >> 4) * 4 + reg;
                        float p = __expf(S[i][j][reg] * 0.125f) * rinv[qrow];
                        csacc[j] += p;
                        Pl[qrow * 64 + ((kcol & 7) | ((((kcol >> 3) ^ (qrow & 7))) << 3))] = f2bf(p);
                    }
                }
            }
#pragma unroll
            for (int j = 0; j < 2; ++j) {
                float v = csacc[j];
                v += __shfl_xor(v, 16);
                v += __shfl_xor(v, 32);
                if (l < 16) atomicAdd(&cs[sub * 64 + wc * 32 + j * 16 + l], v);
            }
            __syncthreads();
#pragma unroll
            for (int it2 = 0; it2 < 4; ++it2) {
                int chunk = it2 * 256 + tid;
                int row = chunk >> 3, g = chunk & 7;
                uint4 pv = Pl4[row * 8 + (g ^ (row & 7))];
                float4 lo, hi;
                lo.x = bflo2f(pv.x); lo.y = bfhi2f(pv.x);
                lo.z = bflo2f(pv.y); lo.w = bfhi2f(pv.y);
                hi.x = bflo2f(pv.z); hi.y = bfhi2f(pv.z);
                hi.z = bflo2f(pv.w); hi.w = bfhi2f(pv.w);
                float* dst = attn + hbb + (size_t)(qt * 128 + row) * B + kbase + g * 8;
                *(float4*)dst = lo;
                *(float4*)(dst + 4) = hi;
            }
#pragma unroll
            for (int km = 0; km < 2; ++km) {
                int gsel = km * 4 + (l >> 4);
                bf16x8 pa[4], vb[2];
#pragma unroll
                for (int i = 0; i < 4; ++i) {
                    int q = wr * 64 + i * 16 + (l & 15);
                    pa[i] = __builtin_bit_cast(bf16x8, Pl4[q * 8 + (gsel ^ (q & 7))]);
                }
#pragma unroll
                for (int j = 0; j < 2; ++j) {
                    int d = wc * 32 + j * 16 + (l & 15);
                    vb[j] = __builtin_bit_cast(bf16x8, Vt[d * 8 + (gsel ^ (d & 7))]);
                }
#pragma unroll
                for (int i = 0; i < 4; ++i)
#pragma unroll
                    for (int j = 0; j < 2; ++j)
                        O[i][j] = __builtin_amdgcn_mfma_f32_16x16x32_bf16(pa[i], vb[j], O[i][j], 0, 0, 0);
            }
            __syncthreads();
        }
    }

    if constexpr (PHASE == 1) {
#pragma unroll
        for (int i = 0; i < 4; ++i)
#pragma unroll
            for (int reg = 0; reg < 4; ++reg) {
                float v = rsum[i][reg];
                v += __shfl_xor(v, 1); v += __shfl_xor(v, 2);
                v += __shfl_xor(v, 4); v += __shfl_xor(v, 8);
                if ((l & 15) == 0)
                    atomicAdd(&rowsum_out[h * B + qt * 128 + wr * 64 + i * 16 + (l >> 4) * 4 + reg], v);
            }
    } else {
        for (int i = tid; i < 512; i += 256)
            atomicAdd(&colsum[h * B + ct * 512 + i], cs[i]);
#pragma unroll
        for (int i = 0; i < 4; ++i)
#pragma unroll
            for (int j = 0; j < 2; ++j)
#pragma unroll
                for (int reg = 0; reg < 4; ++reg) {
                    int qrow = wr * 64 + i * 16 + (l >> 4) * 4 + reg;
                    ovp[((size_t)ct * B + qt * 128 + qrow) * DIM + h * 64 + wc * 32 + j * 16 + (l & 15)] =
                        O[i][j][reg];
                }
    }
}

// ---------------------------------------------------------------------------
// K5: maskfix with fused per-block top-5 (deterministic redundant scan).
// grid (32 rt, 8 h).
// ---------------------------------------------------------------------------
__global__ __launch_bounds__(256) void maskfix_topk(float* __restrict__ attn,
                                                    const float* __restrict__ v_f32,
                                                    const float* __restrict__ colsum,
                                                    const float* __restrict__ ovp,
                                                    unsigned short* __restrict__ ovbf) {
    int rt = blockIdx.x;
    int h = blockIdx.y;
    int tid = threadIdx.x;
    __shared__ float v[B];
    __shared__ float bv[256];
    __shared__ int bi[256];
    __shared__ float Pl[5][64];
    __shared__ float Vl[5][64];
    __shared__ int tix[5];
    for (int i = tid; i < B; i += 256) v[i] = colsum[h * B + i];
    __syncthreads();
    for (int it = 0; it < 5; ++it) {
        float best = -1e30f;
        int bidx = 0;
        for (int i = tid; i < B; i += 256) {
            float x = v[i];
            if (x > best || (x == best && i < bidx)) { best = x; bidx = i; }
        }
        bv[tid] = best; bi[tid] = bidx;
        __syncthreads();
        for (int s = 128; s > 0; s >>= 1) {
            if (tid < s) {
                if (bv[tid + s] > bv[tid] ||
                    (bv[tid + s] == bv[tid] && bi[tid + s] < bi[tid])) {
                    bv[tid] = bv[tid + s]; bi[tid] = bi[tid + s];
                }
            }
            __syncthreads();
        }
        if (tid == 0) { tix[it] = bi[0]; v[bi[0]] = -1e30f; }
        __syncthreads();
    }
    size_t abase = (size_t)h * B * B + (size_t)(rt * 64) * B;
    for (int t = tid; t < 320; t += 256) {
        int i = t / 64, q = t % 64;
        Pl[i][q] = attn[abase + (size_t)q * B + tix[i]];
        Vl[i][q] = v_f32[(size_t)tix[i] * DIM + h * 64 + q];
    }
    __syncthreads();
    for (int t = tid; t < 320; t += 256) {
        int i = t / 64, q = t % 64;
        attn[abase + (size_t)q * B + tix[i]] = 0.f;
    }
    int tx = tid % 16, ty = tid / 16;
    float corr[4][4] = {};
#pragma unroll
    for (int i = 0; i < 5; ++i)
#pragma unroll
        for (int a = 0; a < 4; ++a)
#pragma unroll
            for (int b2 = 0; b2 < 4; ++b2)
                corr[a][b2] += Pl[i][ty * 4 + a] * Vl[i][tx * 4 + b2];
#pragma unroll
    for (int a = 0; a < 4; ++a) {
        size_t row = (size_t)(rt * 64 + ty * 4 + a);
        size_t col = h * 64 + tx * 4;
        float4 s0 = *(const float4*)(ovp + ((size_t)0 * B + row) * DIM + col);
        float4 s1 = *(const float4*)(ovp + ((size_t)1 * B + row) * DIM + col);
        float4 s2 = *(const float4*)(ovp + ((size_t)2 * B + row) * DIM + col);
        float4 s3 = *(const float4*)(ovp + ((size_t)3 * B + row) * DIM + col);
        ushort4 u;
        u.x = f2bf(s0.x + s1.x + s2.x + s3.x - corr[a][0]);
        u.y = f2bf(s0.y + s1.y + s2.y + s3.y - corr[a][1]);
        u.z = f2bf(s0.z + s1.z + s2.z + s3.z - corr[a][2]);
        u.w = f2bf(s0.w + s1.w + s2.w + s3.w - corr[a][3]);
        *(ushort4*)(ovbf + row * DIM + col) = u;
    }
}

// ---------------------------------------------------------------------------
// K7: y = ov @ W_proj^T + b_proj via bf16 MFMA; fused BN partial sums.
// ---------------------------------------------------------------------------
__global__ __launch_bounds__(256) void proj_gemm_mfma(const unsigned short* __restrict__ ovbf,
                                                      const unsigned short* __restrict__ wpbf,
                                                      const float* __restrict__ bproj,
                                                      float* __restrict__ y,
                                                      float* __restrict__ sums,
                                                      float* __restrict__ ssums) {
    int nt = blockIdx.x;   // 0..7
    int mt = blockIdx.y;   // 0..15
    __shared__ uint4 Ax[128 * 8];
    __shared__ uint4 Bw[64 * 8];
    __shared__ float sb[64];
    __shared__ float qb[64];
    int tid = threadIdx.x;
    int l = tid & 63, wid = tid >> 6;
    int wr = wid >> 1, wc = wid & 1;
    if (tid < 64) { sb[tid] = 0.f; qb[tid] = 0.f; }
    const uint4* a4 = (const uint4*)ovbf;
    const uint4* b4 = (const uint4*)wpbf;
    f32x4 acc[4][2];
#pragma unroll
    for (int i = 0; i < 4; ++i)
#pragma unroll
        for (int j = 0; j < 2; ++j) acc[i][j] = (f32x4){0.f, 0.f, 0.f, 0.f};

    for (int kt = 0; kt < 8; ++kt) {
        int kg = kt * 8;
#pragma unroll
        for (int it = 0; it < 4; ++it) {
            int chunk = it * 256 + tid;
            int row = chunk >> 3, slot = chunk & 7;
            Ax[row * 8 + (slot ^ (row & 7))] = a4[(size_t)(mt * 128 + row) * 64 + kg + slot];
        }
#pragma unroll
        for (int it = 0; it < 2; ++it) {
            int chunk = it * 256 + tid;
            int row = chunk >> 3, slot = chunk & 7;
            Bw[row * 8 + (slot ^ (row & 7))] = b4[(size_t)(nt * 64 + row) * 64 + kg + slot];
        }
        __syncthreads();
#pragma unroll
        for (int km = 0; km < 2; ++km) {
            int gsel = km * 4 + (l >> 4);
            bf16x8 a[4], b[2];
#pragma unroll
            for (int i = 0; i < 4; ++i) {
                int row = wr * 64 + i * 16 + (l & 15);
                a[i] = __builtin_bit_cast(bf16x8, Ax[row * 8 + (gsel ^ (row & 7))]);
            }
#pragma unroll
            for (int j = 0; j < 2; ++j) {
                int row = wc * 32 + j * 16 + (l & 15);
                b[j] = __builtin_bit_cast(bf16x8, Bw[row * 8 + (gsel ^ (row & 7))]);
            }
#pragma unroll
            for (int i = 0; i < 4; ++i)
#pragma unroll
                for (int j = 0; j < 2; ++j)
                    acc[i][j] = __builtin_amdgcn_mfma_f32_16x16x32_bf16(a[i], b[j], acc[i][j], 0, 0, 0);
        }
        __syncthreads();
    }
    float ls[2] = {0.f, 0.f};
    float lq[2] = {0.f, 0.f};
#pragma unroll
    for (int i = 0; i < 4; ++i)
#pragma unroll
        for (int j = 0; j < 2; ++j) {
            int col = nt * 64 + wc * 32 + j * 16 + (l & 15);
            float bp = bproj[col];
#pragma unroll
            for (int reg = 0; reg < 4; ++reg) {
                int row = mt * 128 + wr * 64 + i * 16 + (l >> 4) * 4 + reg;
                float c = acc[i][j][reg] + bp;
                y[(size_t)row * DIM + col] = c;
                ls[j] += c; lq[j] += c * c;
            }
        }
#pragma unroll
    for (int j = 0; j < 2; ++j) {
        atomicAdd(&sb[wc * 32 + j * 16 + (l & 15)], ls[j]);
        atomicAdd(&qb[wc * 32 + j * 16 + (l & 15)], lq[j]);
    }
    __syncthreads();
    if (tid < 64) {
        atomicAdd(&sums[nt * 64 + tid], sb[tid]);
        atomicAdd(&ssums[nt * 64 + tid], qb[tid]);
    }
}

// ---------------------------------------------------------------------------
// K9: out = relu(gamma*(y-mean)*rstd + beta); mean/rstd from sums inline
// ---------------------------------------------------------------------------
__global__ __launch_bounds__(256) void bn_apply(const float* __restrict__ y,
                                                const float* __restrict__ sums,
                                                const float* __restrict__ ssums,
                                                const float* __restrict__ gamma,
                                                const float* __restrict__ beta,
                                                float* __restrict__ out) {
    int t = blockIdx.x * 256 + threadIdx.x;
    int c4 = (t % 128) * 4;
    size_t r = t / 128;
    if (r >= B) return;
    float4 s = *(const float4*)(sums + c4);
    float4 q = *(const float4*)(ssums + c4);
    float4 m, rs;
    m.x = s.x * (1.0f / B); m.y = s.y * (1.0f / B);
    m.z = s.z * (1.0f / B); m.w = s.w * (1.0f / B);
    rs.x = rsqrtf(q.x * (1.0f / B) - m.x * m.x + 1e-5f);
    rs.y = rsqrtf(q.y * (1.0f / B) - m.y * m.y + 1e-5f);
    rs.z = rsqrtf(q.z * (1.0f / B) - m.z * m.z + 1e-5f);
    rs.w = rsqrtf(q.w * (1.0f / B) - m.w * m.w + 1e-5f);
    float4 v = *(const float4*)(y + r * DIM + c4);
    float4 g = *(const float4*)(gamma + c4);
    float4 bt = *(const float4*)(beta + c4);
    float4 o;
    o.x = fmaxf(0.f, g.x * (v.x - m.x) * rs.x + bt.x);
    o.y = fmaxf(0.f, g.y * (v.y - m.y) * rs.y + bt.y);
    o.z = fmaxf(0.f, g.z * (v.z - m.z) * rs.z + bt.z);
    o.w = fmaxf(0.f, g.w * (v.w - m.w) * rs.w + bt.w);
    *(float4*)(out + r * DIM + c4) = o;
}

// ---------------------------------------------------------------------------
extern "C" void kernel_launch(void* const* d_in, const int* in_sizes, int n_in,
                              void* d_out, int out_size, void* d_ws, size_t ws_size,
                              hipStream_t stream) {
    const float* x = (const float*)d_in[0];
    const float* W_qkv = (const float*)d_in[1];
    const float* W_proj = (const float*)d_in[2];
    const float* b_proj = (const float*)d_in[3];
    const float* bn_gamma = (const float*)d_in[4];
    const float* bn_beta = (const float*)d_in[5];

    float* out0 = (float*)d_out;                         // [2048,512]
    float* attn = (float*)d_out + OUT0_ELEMS;            // [8,2048,2048]

    float* ws = (float*)d_ws;
    float* v_f32 = ws;                                   // 1,048,576 f
    float* ovp = v_f32 + OUT0_ELEMS;                     // 4,194,304 f
    float* y = ovp + 4 * OUT0_ELEMS;                     // 1,048,576 f
    // zero region (contiguous, one memset): rowsum, colsum, sums, ssums
    float* rowsum = y + OUT0_ELEMS;                      // 16,384 f
    float* colsum = rowsum + NH * B;                     // 16,384 f
    float* sums = colsum + NH * B;                       // 512 f
    float* ssums = sums + DIM;                           // 512 f
    unsigned short* qkbf = (unsigned short*)(ssums + DIM);       // B*1024 us
    unsigned short* vT = qkbf + (size_t)B * 1024;                // NH*HD*B us
    unsigned short* wpbf = vT + (size_t)NH * HD * B;             // 512*512 us
    unsigned short* ovbf = wpbf + (size_t)DIM * DIM;             // B*DIM us
    // xbf (2 MB) + wT (1.5 MB) alias ovp: consumed by gemm_qkv_mfma, which
    // completes before attn_pass<2> writes ovp.
    unsigned short* xbf = (unsigned short*)ovp;
    unsigned short* wT = xbf + (size_t)B * 512;

    hipMemsetAsync(rowsum, 0, (2 * NH * B + 2 * DIM) * sizeof(float), stream);

    prep_cast<<<1280 + 192, 256, 0, stream>>>(x, W_proj, W_qkv, xbf, wpbf, wT);
    gemm_qkv_mfma<<<dim3(QKVN / 64, B / 128), 256, 0, stream>>>(xbf, wT, v_f32, qkbf, vT);
    attn_pass<1><<<dim3(4, 16, NH), 256, 0, stream>>>(qkbf, vT, nullptr, rowsum,
                                                      attn, colsum, ovp);
    attn_pass<2><<<dim3(4, 16, NH), 256, 0, stream>>>(qkbf, vT, rowsum, nullptr,
                                                      attn, colsum, ovp);
    maskfix_topk<<<dim3(B / 64, NH), 256, 0, stream>>>(attn, v_f32, colsum, ovp, ovbf);
    proj_gemm_mfma<<<dim3(DIM / 64, B / 128), 256, 0, stream>>>(ovbf, wpbf, b_proj,
                                                                y, sums, ssums);
    bn_apply<<<(B * DIM / 4 + 255) / 256, 256, 0, stream>>>(y, sums, ssums,
                                                            bn_gamma, bn_beta, out0);
}

// Round 14
// 99.317 us; speedup vs baseline: 1.3298x; 1.0525x over previous
//
#include <hip/hip_runtime.h>
#include <hip/hip_bf16.h>

#define B 2048
#define NH 8
#define HD 64
#define DIM 512
#define QKVN 1536
#define OUT0_ELEMS ((size_t)B * DIM)        // 1,048,576

typedef float f32x4 __attribute__((ext_vector_type(4)));
typedef __bf16 bf16x8 __attribute__((ext_vector_type(8)));

static __device__ __forceinline__ unsigned short f2bf(float f) {
    unsigned int u = __builtin_bit_cast(unsigned int, f);
    u += 0x7fffu + ((u >> 16) & 1u);   // RNE
    return (unsigned short)(u >> 16);
}
static __device__ __forceinline__ float bfhi2f(unsigned int u) {
    return __builtin_bit_cast(float, u & 0xffff0000u);
}
static __device__ __forceinline__ float bflo2f(unsigned int u) {
    return __builtin_bit_cast(float, u << 16);
}

// ---------------------------------------------------------------------------
// K0: all input casts + accumulator zeroing in one launch.
// blocks [0,1280): x (1M) + W_proj (256K) flat cast
// blocks [1280,1472): W_qkv cast+transpose -> wT [1536][512]
// blocks [1472,1505): zero rowsum/colsum/sums/ssums (33792 floats)
// ---------------------------------------------------------------------------
__global__ __launch_bounds__(256) void prep_cast(const float* __restrict__ x,
                                                 const float* __restrict__ wp,
                                                 const float* __restrict__ wqkv,
                                                 unsigned short* __restrict__ xbf,
                                                 unsigned short* __restrict__ wpbf,
                                                 unsigned short* __restrict__ wT,
                                                 float* __restrict__ zero_region) {
    int bx = blockIdx.x;
    int tid = threadIdx.x;
    if (bx < 1280) {
        size_t t = (size_t)bx * 256 + tid;
        const float4* src;
        ushort4* dst;
        size_t idx;
        if (t < 262144) { src = (const float4*)x; dst = (ushort4*)xbf; idx = t; }
        else            { src = (const float4*)wp; dst = (ushort4*)wpbf; idx = t - 262144; }
        float4 v = src[idx];
        ushort4 u;
        u.x = f2bf(v.x); u.y = f2bf(v.y); u.z = f2bf(v.z); u.w = f2bf(v.w);
        dst[idx] = u;
        return;
    }
    if (bx >= 1472) {
        int idx = (bx - 1472) * 256 + tid;
        if (idx < 8448)   // (2*NH*B + 2*DIM)/4 float4s
            ((float4*)zero_region)[idx] = make_float4(0.f, 0.f, 0.f, 0.f);
        return;
    }
    int b = bx - 1280;                 // 0..191
    int n0 = (b % 24) * 64;
    int k0 = (b / 24) * 64;
    __shared__ unsigned short T[64][72];   // [n][k]
#pragma unroll
    for (int it = 0; it < 4; ++it) {
        int chunk = it * 256 + tid;
        int r = chunk >> 4, c4 = (chunk & 15) * 4;
        float4 v = *(const float4*)(wqkv + (size_t)(k0 + r) * QKVN + n0 + c4);
        T[c4 + 0][r] = f2bf(v.x); T[c4 + 1][r] = f2bf(v.y);
        T[c4 + 2][r] = f2bf(v.z); T[c4 + 3][r] = f2bf(v.w);
    }
    __syncthreads();
#pragma unroll
    for (int it = 0; it < 2; ++it) {
        int chunk = it * 256 + tid;
        int r = chunk >> 3, c8 = (chunk & 7) * 8;
        ushort4 u0, u1;
        u0.x = T[r][c8 + 0]; u0.y = T[r][c8 + 1]; u0.z = T[r][c8 + 2]; u0.w = T[r][c8 + 3];
        u1.x = T[r][c8 + 4]; u1.y = T[r][c8 + 5]; u1.z = T[r][c8 + 6]; u1.w = T[r][c8 + 7];
        *(ushort4*)(wT + (size_t)(n0 + r) * 512 + k0 + c8) = u0;
        *(ushort4*)(wT + (size_t)(n0 + r) * 512 + k0 + c8 + 4) = u1;
    }
}

// ---------------------------------------------------------------------------
// K1: qkv = x @ W_qkv via bf16 MFMA. Tile 128m x 64n, 4 waves (2x2).
// q cols (nt<8) are pre-scaled by the attention scale 0.125 (exact pow2)
// before the bf16 cast, so attn passes can skip the per-element scale.
// k cols -> qkbf unscaled; v cols -> vT[h][d][k] (transposed) + v_f32.
// ---------------------------------------------------------------------------
__global__ __launch_bounds__(256) void gemm_qkv_mfma(const unsigned short* __restrict__ xbf,
                                                     const unsigned short* __restrict__ wT,
                                                     float* __restrict__ v_f32,
                                                     unsigned short* __restrict__ qkbf,
                                                     unsigned short* __restrict__ vT) {
    int nt = blockIdx.x;   // 0..23
    int mt = blockIdx.y;   // 0..15
    __shared__ uint4 Ax[128 * 8];
    __shared__ uint4 Bw[64 * 8];
    int tid = threadIdx.x;
    int l = tid & 63, wid = tid >> 6;
    int wr = wid >> 1, wc = wid & 1;
    const uint4* x4 = (const uint4*)xbf;
    const uint4* w4 = (const uint4*)wT;
    f32x4 acc[4][2];
#pragma unroll
    for (int i = 0; i < 4; ++i)
#pragma unroll
        for (int j = 0; j < 2; ++j) acc[i][j] = (f32x4){0.f, 0.f, 0.f, 0.f};

    for (int kt = 0; kt < 8; ++kt) {
        int kg = kt * 8;
#pragma unroll
        for (int it = 0; it < 4; ++it) {
            int chunk = it * 256 + tid;
            int row = chunk >> 3, slot = chunk & 7;
            Ax[row * 8 + (slot ^ (row & 7))] = x4[(size_t)(mt * 128 + row) * 64 + kg + slot];
        }
#pragma unroll
        for (int it = 0; it < 2; ++it) {
            int chunk = it * 256 + tid;
            int row = chunk >> 3, slot = chunk & 7;
            Bw[row * 8 + (slot ^ (row & 7))] = w4[(size_t)(nt * 64 + row) * 64 + kg + slot];
        }
        __syncthreads();
#pragma unroll
        for (int km = 0; km < 2; ++km) {
            int gsel = km * 4 + (l >> 4);
            bf16x8 a[4], b[2];
#pragma unroll
            for (int i = 0; i < 4; ++i) {
                int row = wr * 64 + i * 16 + (l & 15);
                a[i] = __builtin_bit_cast(bf16x8, Ax[row * 8 + (gsel ^ (row & 7))]);
            }
#pragma unroll
            for (int j = 0; j < 2; ++j) {
                int row = wc * 32 + j * 16 + (l & 15);
                b[j] = __builtin_bit_cast(bf16x8, Bw[row * 8 + (gsel ^ (row & 7))]);
            }
#pragma unroll
            for (int i = 0; i < 4; ++i)
#pragma unroll
                for (int j = 0; j < 2; ++j)
                    acc[i][j] = __builtin_amdgcn_mfma_f32_16x16x32_bf16(a[i], b[j], acc[i][j], 0, 0, 0);
        }
        __syncthreads();
    }
    if (nt < 16) {
        float qscale = (nt < 8) ? 0.125f : 1.0f;   // exact pow2: exponent shift only
#pragma unroll
        for (int i = 0; i < 4; ++i)
#pragma unroll
            for (int j = 0; j < 2; ++j)
#pragma unroll
                for (int reg = 0; reg < 4; ++reg) {
                    int row = mt * 128 + wr * 64 + i * 16 + (l >> 4) * 4 + reg;
                    int col = nt * 64 + wc * 32 + j * 16 + (l & 15);
                    qkbf[(size_t)row * 1024 + col] = f2bf(acc[i][j][reg] * qscale);
                }
    } else {
        int h = nt - 16;   // head
#pragma unroll
        for (int i = 0; i < 4; ++i)
#pragma unroll
            for (int j = 0; j < 2; ++j) {
                int k0r = mt * 128 + wr * 64 + i * 16 + (l >> 4) * 4;
                int d = wc * 32 + j * 16 + (l & 15);
                uint2 pk;
                pk.x = (unsigned)f2bf(acc[i][j][0]) | ((unsigned)f2bf(acc[i][j][1]) << 16);
                pk.y = (unsigned)f2bf(acc[i][j][2]) | ((unsigned)f2bf(acc[i][j][3]) << 16);
                *(uint2*)(vT + ((size_t)(h * 64 + d) * 2048 + k0r)) = pk;
#pragma unroll
                for (int reg = 0; reg < 4; ++reg)
                    v_f32[(size_t)(k0r + reg) * DIM + h * 64 + d] = acc[i][j][reg];
            }
    }
}

// ---------------------------------------------------------------------------
// K3: attention pass. PHASE 1: rowsums only. PHASE 2: recompute QK^T,
//     normalize, vector-write P (from bf16 LDS stash), colsum, PV via MFMA.
// Q is pre-scaled by 0.125, so S is already the scaled logit: P = exp(S).
// grid (4 ct, 16 qt of 128q, 8 h) = 512 blocks, 4 waves 2x2.
// ---------------------------------------------------------------------------
template<int PHASE>
__global__ __launch_bounds__(256) void attn_pass(const unsigned short* __restrict__ qkbf,
                                                 const unsigned short* __restrict__ vT,
                                                 const float* __restrict__ rowsum_in,
                                                 float* __restrict__ rowsum_out,
                                                 float* __restrict__ attn,
                                                 float* __restrict__ colsum,
                                                 float* __restrict__ ovp) {
    int ct = blockIdx.x, qt = blockIdx.y, h = blockIdx.z;
    int tid = threadIdx.x;
    int l = tid & 63;
    int wid = tid >> 6;
    int wr = wid >> 1;
    int wc = wid & 1;

    __shared__ uint4 Qs[128 * 8];
    __shared__ uint4 Ks[64 * 8];
    __shared__ uint4 Vt[64 * 8];
    __shared__ uint4 Pl4[128 * 8];
    __shared__ float cs[512];
    __shared__ float rinv[128];
    unsigned short* Pl = (unsigned short*)Pl4;

    const uint4* src = (const uint4*)qkbf;   // row = 128 uint4
#pragma unroll
    for (int it = 0; it < 4; ++it) {
        int chunk = it * 256 + tid;
        int row = chunk >> 3, slot = chunk & 7;
        Qs[row * 8 + (slot ^ (row & 7))] = src[(size_t)(qt * 128 + row) * 128 + h * 8 + slot];
    }
    if constexpr (PHASE == 2) {
        if (tid < 128) rinv[tid] = 1.0f / rowsum_in[h * B + qt * 128 + tid];
        if (tid < 256) { cs[tid] = 0.f; cs[tid + 256] = 0.f; }
    }

    float rsum[4][4];
    f32x4 O[4][2];
    if constexpr (PHASE == 1) {
#pragma unroll
        for (int i = 0; i < 4; ++i)
#pragma unroll
            for (int r = 0; r < 4; ++r) rsum[i][r] = 0.f;
    } else {
#pragma unroll
        for (int i = 0; i < 4; ++i)
#pragma unroll
            for (int j = 0; j < 2; ++j) O[i][j] = (f32x4){0.f, 0.f, 0.f, 0.f};
    }

    size_t hbb = (size_t)h * B * B;
    for (int sub = 0; sub < 8; ++sub) {
        int kbase = ct * 512 + sub * 64;
#pragma unroll
        for (int it = 0; it < 2; ++it) {
            int chunk = it * 256 + tid;
            int row = chunk >> 3, slot = chunk & 7;
            Ks[row * 8 + (slot ^ (row & 7))] = src[(size_t)(kbase + row) * 128 + 64 + h * 8 + slot];
        }
        if constexpr (PHASE == 2) {
#pragma unroll
            for (int it = 0; it < 2; ++it) {
                int chunk = it * 256 + tid;
                int d = chunk >> 3, g = chunk & 7;
                Vt[d * 8 + (g ^ (d & 7))] =
                    *(const uint4*)(vT + ((size_t)(h * 64 + d) * 2048 + kbase + g * 8));
            }
        }
        __syncthreads();

        // ---- QK^T ----
        f32x4 S[4][2];
#pragma unroll
        for (int i = 0; i < 4; ++i)
#pragma unroll
            for (int j = 0; j < 2; ++j) S[i][j] = (f32x4){0.f, 0.f, 0.f, 0.f};
#pragma unroll
        for (int km = 0; km < 2; ++km) {
            int gsel = km * 4 + (l >> 4);
            bf16x8 aq[4], bk[2];
#pragma unroll
            for (int i = 0; i < 4; ++i) {
                int row = wr * 64 + i * 16 + (l & 15);
                aq[i] = __builtin_bit_cast(bf16x8, Qs[row * 8 + (gsel ^ (row & 7))]);
            }
#pragma unroll
            for (int j = 0; j < 2; ++j) {
                int row = wc * 32 + j * 16 + (l & 15);
                bk[j] = __builtin_bit_cast(bf16x8, Ks[row * 8 + (gsel ^ (row & 7))]);
            }
#pragma unroll
            for (int i = 0; i < 4; ++i)
#pragma unroll
                for (int j = 0; j < 2; ++j)
                    S[i][j] = __builtin_amdgcn_mfma_f32_16x16x32_bf16(aq[i], bk[j], S[i][j], 0, 0, 0);
        }

        if constexpr (PHASE == 1) {
#pragma unroll
            for (int i = 0; i < 4; ++i)
#pragma unroll
                for (int j = 0; j < 2; ++j)
#pragma unroll
                    for (int reg = 0; reg < 4; ++reg)
                        rsum[i][reg] += __expf(S[i][j][reg]);
            __syncthreads();
        } else {
            float csacc[2] = {0.f, 0.f};
#pragma unroll
            for (int i = 0; i < 4; ++i) {
#pragma unroll
                for (int j = 0; j < 2; ++j) {
                    int kcol = wc * 32 + j * 16 + (l & 15);
#pragma unroll
                    for (int reg = 0; reg < 4; ++reg) {
                        int qrow = wr * 64 + i * 16 + (l >> 4) * 4 + reg;
                        float p = __expf(S[i][j][reg]) * rinv[qrow];
                        csacc[j] += p;
                        Pl[qrow * 64 + ((kcol & 7) | ((((kcol >> 3) ^ (qrow & 7))) << 3))] = f2bf(p);
                    }
                }
            }
#pragma unroll
            for (int j = 0; j < 2; ++j) {
                float v = csacc[j];
                v += __shfl_xor(v, 16);
                v += __shfl_xor(v, 32);
                if (l < 16) atomicAdd(&cs[sub * 64 + wc * 32 + j * 16 + l], v);
            }
            __syncthreads();
#pragma unroll
            for (int it2 = 0; it2 < 4; ++it2) {
                int chunk = it2 * 256 + tid;
                int row = chunk >> 3, g = chunk & 7;
                uint4 pv = Pl4[row * 8 + (g ^ (row & 7))];
                float4 lo, hi;
                lo.x = bflo2f(pv.x); lo.y = bfhi2f(pv.x);
                lo.z = bflo2f(pv.y); lo.w = bfhi2f(pv.y);
                hi.x = bflo2f(pv.z); hi.y = bfhi2f(pv.z);
                hi.z = bflo2f(pv.w); hi.w = bfhi2f(pv.w);
                float* dst = attn + hbb + (size_t)(qt * 128 + row) * B + kbase + g * 8;
                *(float4*)dst = lo;
                *(float4*)(dst + 4) = hi;
            }
#pragma unroll
            for (int km = 0; km < 2; ++km) {
                int gsel = km * 4 + (l >> 4);
                bf16x8 pa[4], vb[2];
#pragma unroll
                for (int i = 0; i < 4; ++i) {
                    int q = wr * 64 + i * 16 + (l & 15);
                    pa[i] = __builtin_bit_cast(bf16x8, Pl4[q * 8 + (gsel ^ (q & 7))]);
                }
#pragma unroll
                for (int j = 0; j < 2; ++j) {
                    int d = wc * 32 + j * 16 + (l & 15);
                    vb[j] = __builtin_bit_cast(bf16x8, Vt[d * 8 + (gsel ^ (d & 7))]);
                }
#pragma unroll
                for (int i = 0; i < 4; ++i)
#pragma unroll
                    for (int j = 0; j < 2; ++j)
                        O[i][j] = __builtin_amdgcn_mfma_f32_16x16x32_bf16(pa[i], vb[j], O[i][j], 0, 0, 0);
            }
            __syncthreads();
        }
    }

    if constexpr (PHASE == 1) {
#pragma unroll
        for (int i = 0; i < 4; ++i)
#pragma unroll
            for (int reg = 0; reg < 4; ++reg) {
                float v = rsum[i][reg];
                v += __shfl_xor(v, 1); v += __shfl_xor(v, 2);
                v += __shfl_xor(v, 4); v += __shfl_xor(v, 8);
                if ((l & 15) == 0)
                    atomicAdd(&rowsum_out[h * B + qt * 128 + wr * 64 + i * 16 + (l >> 4) * 4 + reg], v);
            }
    } else {
        for (int i = tid; i < 512; i += 256)
            atomicAdd(&colsum[h * B + ct * 512 + i], cs[i]);
#pragma unroll
        for (int i = 0; i < 4; ++i)
#pragma unroll
            for (int j = 0; j < 2; ++j)
#pragma unroll
                for (int reg = 0; reg < 4; ++reg) {
                    int qrow = wr * 64 + i * 16 + (l >> 4) * 4 + reg;
                    ovp[((size_t)ct * B + qt * 128 + qrow) * DIM + h * 64 + wc * 32 + j * 16 + (l & 15)] =
                        O[i][j][reg];
                }
    }
}

// ---------------------------------------------------------------------------
// K5: maskfix with fused per-block top-5 (deterministic redundant scan).
// grid (32 rt, 8 h).
// ---------------------------------------------------------------------------
__global__ __launch_bounds__(256) void maskfix_topk(float* __restrict__ attn,
                                                    const float* __restrict__ v_f32,
                                                    const float* __restrict__ colsum,
                                                    const float* __restrict__ ovp,
                                                    unsigned short* __restrict__ ovbf) {
    int rt = blockIdx.x;
    int h = blockIdx.y;
    int tid = threadIdx.x;
    __shared__ float v[B];
    __shared__ float bv[256];
    __shared__ int bi[256];
    __shared__ float Pl[5][64];
    __shared__ float Vl[5][64];
    __shared__ int tix[5];
    for (int i = tid; i < B; i += 256) v[i] = colsum[h * B + i];
    __syncthreads();
    for (int it = 0; it < 5; ++it) {
        float best = -1e30f;
        int bidx = 0;
        for (int i = tid; i < B; i += 256) {
            float x = v[i];
            if (x > best || (x == best && i < bidx)) { best = x; bidx = i; }
        }
        bv[tid] = best; bi[tid] = bidx;
        __syncthreads();
        for (int s = 128; s > 0; s >>= 1) {
            if (tid < s) {
                if (bv[tid + s] > bv[tid] ||
                    (bv[tid + s] == bv[tid] && bi[tid + s] < bi[tid])) {
                    bv[tid] = bv[tid + s]; bi[tid] = bi[tid + s];
                }
            }
            __syncthreads();
        }
        if (tid == 0) { tix[it] = bi[0]; v[bi[0]] = -1e30f; }
        __syncthreads();
    }
    size_t abase = (size_t)h * B * B + (size_t)(rt * 64) * B;
    for (int t = tid; t < 320; t += 256) {
        int i = t / 64, q = t % 64;
        Pl[i][q] = attn[abase + (size_t)q * B + tix[i]];
        Vl[i][q] = v_f32[(size_t)tix[i] * DIM + h * 64 + q];
    }
    __syncthreads();
    for (int t = tid; t < 320; t += 256) {
        int i = t / 64, q = t % 64;
        attn[abase + (size_t)q * B + tix[i]] = 0.f;
    }
    int tx = tid % 16, ty = tid / 16;
    float corr[4][4] = {};
#pragma unroll
    for (int i = 0; i < 5; ++i)
#pragma unroll
        for (int a = 0; a < 4; ++a)
#pragma unroll
            for (int b2 = 0; b2 < 4; ++b2)
                corr[a][b2] += Pl[i][ty * 4 + a] * Vl[i][tx * 4 + b2];
#pragma unroll
    for (int a = 0; a < 4; ++a) {
        size_t row = (size_t)(rt * 64 + ty * 4 + a);
        size_t col = h * 64 + tx * 4;
        float4 s0 = *(const float4*)(ovp + ((size_t)0 * B + row) * DIM + col);
        float4 s1 = *(const float4*)(ovp + ((size_t)1 * B + row) * DIM + col);
        float4 s2 = *(const float4*)(ovp + ((size_t)2 * B + row) * DIM + col);
        float4 s3 = *(const float4*)(ovp + ((size_t)3 * B + row) * DIM + col);
        ushort4 u;
        u.x = f2bf(s0.x + s1.x + s2.x + s3.x - corr[a][0]);
        u.y = f2bf(s0.y + s1.y + s2.y + s3.y - corr[a][1]);
        u.z = f2bf(s0.z + s1.z + s2.z + s3.z - corr[a][2]);
        u.w = f2bf(s0.w + s1.w + s2.w + s3.w - corr[a][3]);
        *(ushort4*)(ovbf + row * DIM + col) = u;
    }
}

// ---------------------------------------------------------------------------
// K7: y = ov @ W_proj^T + b_proj via bf16 MFMA; fused BN partial sums.
// ---------------------------------------------------------------------------
__global__ __launch_bounds__(256) void proj_gemm_mfma(const unsigned short* __restrict__ ovbf,
                                                      const unsigned short* __restrict__ wpbf,
                                                      const float* __restrict__ bproj,
                                                      float* __restrict__ y,
                                                      float* __restrict__ sums,
                                                      float* __restrict__ ssums) {
    int nt = blockIdx.x;   // 0..7
    int mt = blockIdx.y;   // 0..15
    __shared__ uint4 Ax[128 * 8];
    __shared__ uint4 Bw[64 * 8];
    __shared__ float sb[64];
    __shared__ float qb[64];
    int tid = threadIdx.x;
    int l = tid & 63, wid = tid >> 6;
    int wr = wid >> 1, wc = wid & 1;
    if (tid < 64) { sb[tid] = 0.f; qb[tid] = 0.f; }
    const uint4* a4 = (const uint4*)ovbf;
    const uint4* b4 = (const uint4*)wpbf;
    f32x4 acc[4][2];
#pragma unroll
    for (int i = 0; i < 4; ++i)
#pragma unroll
        for (int j = 0; j < 2; ++j) acc[i][j] = (f32x4){0.f, 0.f, 0.f, 0.f};

    for (int kt = 0; kt < 8; ++kt) {
        int kg = kt * 8;
#pragma unroll
        for (int it = 0; it < 4; ++it) {
            int chunk = it * 256 + tid;
            int row = chunk >> 3, slot = chunk & 7;
            Ax[row * 8 + (slot ^ (row & 7))] = a4[(size_t)(mt * 128 + row) * 64 + kg + slot];
        }
#pragma unroll
        for (int it = 0; it < 2; ++it) {
            int chunk = it * 256 + tid;
            int row = chunk >> 3, slot = chunk & 7;
            Bw[row * 8 + (slot ^ (row & 7))] = b4[(size_t)(nt * 64 + row) * 64 + kg + slot];
        }
        __syncthreads();
#pragma unroll
        for (int km = 0; km < 2; ++km) {
            int gsel = km * 4 + (l >> 4);
            bf16x8 a[4], b[2];
#pragma unroll
            for (int i = 0; i < 4; ++i) {
                int row = wr * 64 + i * 16 + (l & 15);
                a[i] = __builtin_bit_cast(bf16x8, Ax[row * 8 + (gsel ^ (row & 7))]);
            }
#pragma unroll
            for (int j = 0; j < 2; ++j) {
                int row = wc * 32 + j * 16 + (l & 15);
                b[j] = __builtin_bit_cast(bf16x8, Bw[row * 8 + (gsel ^ (row & 7))]);
            }
#pragma unroll
            for (int i = 0; i < 4; ++i)
#pragma unroll
                for (int j = 0; j < 2; ++j)
                    acc[i][j] = __builtin_amdgcn_mfma_f32_16x16x32_bf16(a[i], b[j], acc[i][j], 0, 0, 0);
        }
        __syncthreads();
    }
    float ls[2] = {0.f, 0.f};
    float lq[2] = {0.f, 0.f};
#pragma unroll
    for (int i = 0; i < 4; ++i)
#pragma unroll
        for (int j = 0; j < 2; ++j) {
            int col = nt * 64 + wc * 32 + j * 16 + (l & 15);
            float bp = bproj[col];
#pragma unroll
            for (int reg = 0; reg < 4; ++reg) {
                int row = mt * 128 + wr * 64 + i * 16 + (l >> 4) * 4 + reg;
                float c = acc[i][j][reg] + bp;
                y[(size_t)row * DIM + col] = c;
                ls[j] += c; lq[j] += c * c;
            }
        }
#pragma unroll
    for (int j = 0; j < 2; ++j) {
        atomicAdd(&sb[wc * 32 + j * 16 + (l & 15)], ls[j]);
        atomicAdd(&qb[wc * 32 + j * 16 + (l & 15)], lq[j]);
    }
    __syncthreads();
    if (tid < 64) {
        atomicAdd(&sums[nt * 64 + tid], sb[tid]);
        atomicAdd(&ssums[nt * 64 + tid], qb[tid]);
    }
}

// ---------------------------------------------------------------------------
// K9: out = relu(gamma*(y-mean)*rstd + beta); mean/rstd from sums inline
// ---------------------------------------------------------------------------
__global__ __launch_bounds__(256) void bn_apply(const float* __restrict__ y,
                                                const float* __restrict__ sums,
                                                const float* __restrict__ ssums,
                                                const float* __restrict__ gamma,
                                                const float* __restrict__ beta,
                                                float* __restrict__ out) {
    int t = blockIdx.x * 256 + threadIdx.x;
    int c4 = (t % 128) * 4;
    size_t r = t / 128;
    if (r >= B) return;
    float4 s = *(const float4*)(sums + c4);
    float4 q = *(const float4*)(ssums + c4);
    float4 m, rs;
    m.x = s.x * (1.0f / B); m.y = s.y * (1.0f / B);
    m.z = s.z * (1.0f / B); m.w = s.w * (1.0f / B);
    rs.x = rsqrtf(q.x * (1.0f / B) - m.x * m.x + 1e-5f);
    rs.y = rsqrtf(q.y * (1.0f / B) - m.y * m.y + 1e-5f);
    rs.z = rsqrtf(q.z * (1.0f / B) - m.z * m.z + 1e-5f);
    rs.w = rsqrtf(q.w * (1.0f / B) - m.w * m.w + 1e-5f);
    float4 v = *(const float4*)(y + r * DIM + c4);
    float4 g = *(const float4*)(gamma + c4);
    float4 bt = *(const float4*)(beta + c4);
    float4 o;
    o.x = fmaxf(0.f, g.x * (v.x - m.x) * rs.x + bt.x);
    o.y = fmaxf(0.f, g.y * (v.y - m.y) * rs.y + bt.y);
    o.z = fmaxf(0.f, g.z * (v.z - m.z) * rs.z + bt.z);
    o.w = fmaxf(0.f, g.w * (v.w - m.w) * rs.w + bt.w);
    *(float4*)(out + r * DIM + c4) = o;
}

// ---------------------------------------------------------------------------
extern "C" void kernel_launch(void* const* d_in, const int* in_sizes, int n_in,
                              void* d_out, int out_size, void* d_ws, size_t ws_size,
                              hipStream_t stream) {
    const float* x = (const float*)d_in[0];
    const float* W_qkv = (const float*)d_in[1];
    const float* W_proj = (const float*)d_in[2];
    const float* b_proj = (const float*)d_in[3];
    const float* bn_gamma = (const float*)d_in[4];
    const float* bn_beta = (const float*)d_in[5];

    float* out0 = (float*)d_out;                         // [2048,512]
    float* attn = (float*)d_out + OUT0_ELEMS;            // [8,2048,2048]

    float* ws = (float*)d_ws;
    float* v_f32 = ws;                                   // 1,048,576 f
    float* ovp = v_f32 + OUT0_ELEMS;                     // 4,194,304 f
    float* y = ovp + 4 * OUT0_ELEMS;                     // 1,048,576 f
    // zero region (contiguous, zeroed by prep_cast): rowsum, colsum, sums, ssums
    float* rowsum = y + OUT0_ELEMS;                      // 16,384 f
    float* colsum = rowsum + NH * B;                     // 16,384 f
    float* sums = colsum + NH * B;                       // 512 f
    float* ssums = sums + DIM;                           // 512 f
    unsigned short* qkbf = (unsigned short*)(ssums + DIM);       // B*1024 us
    unsigned short* vT = qkbf + (size_t)B * 1024;                // NH*HD*B us
    unsigned short* wpbf = vT + (size_t)NH * HD * B;             // 512*512 us
    unsigned short* ovbf = wpbf + (size_t)DIM * DIM;             // B*DIM us
    // xbf (2 MB) + wT (1.5 MB) alias ovp: consumed by gemm_qkv_mfma, which
    // completes before attn_pass<2> writes ovp.
    unsigned short* xbf = (unsigned short*)ovp;
    unsigned short* wT = xbf + (size_t)B * 512;

    prep_cast<<<1280 + 192 + 33, 256, 0, stream>>>(x, W_proj, W_qkv, xbf, wpbf, wT, rowsum);
    gemm_qkv_mfma<<<dim3(QKVN / 64, B / 128), 256, 0, stream>>>(xbf, wT, v_f32, qkbf, vT);
    attn_pass<1><<<dim3(4, 16, NH), 256, 0, stream>>>(qkbf, vT, nullptr, rowsum,
                                                      attn, colsum, ovp);
    attn_pass<2><<<dim3(4, 16, NH), 256, 0, stream>>>(qkbf, vT, rowsum, nullptr,
                                                      attn, colsum, ovp);
    maskfix_topk<<<dim3(B / 64, NH), 256, 0, stream>>>(attn, v_f32, colsum, ovp, ovbf);
    proj_gemm_mfma<<<dim3(DIM / 64, B / 128), 256, 0, stream>>>(ovbf, wpbf, b_proj,
                                                                y, sums, ssums);
    bn_apply<<<(B * DIM / 4 + 255) / 256, 256, 0, stream>>>(y, sums, ssums,
                                                            bn_gamma, bn_beta, out0);
}